// Round 6
// baseline (211.235 us; speedup 1.0000x reference)
//
#include <hip/hip_runtime.h>
#include <stdint.h>

// MultiHeadAttention: S=2048 B=2 D=1024 H=16 HD=64 — fp32 in/out.
// Round 6:
//   - mask_scan: pos[] (exclusive prefix) + cnt.
//   - cvt6: straight fp32->bf16 for xq,xk,xv,wq,wk,wv (no scan dependency).
//   - qkv_gemm_async: TM=128 TN=64, 1536 uniform blocks, global_load_lds
//     staging with XOR chunk permutation (conflict-free frag reads, coalescing
//     preserved), XCD-swizzled flat grid. Epilogue: z=0 Q*scale plain; z=1/2
//     scatter unmasked keys compacted into 64-key-tile chunk-major K / V^T.
//   - attn_kernel: ZERO barriers. K/V^T frags load directly from the tiled
//     global layouts (coalesced 256B segments); P C->A transform through
//     wave-private LDS; no running max; row-sum reduced once at the end.

#define S_ 2048
#define B_ 2
#define D_ 1024
#define H_ 16
#define HD_ 64
#define M_ (S_ * B_)

typedef __bf16 bf16;
typedef bf16 bf16x8 __attribute__((ext_vector_type(8)));
typedef float floatx4 __attribute__((ext_vector_type(4)));

#define QSCALE 0.18033688011112042f   // (1/sqrt(64)) * log2(e)

__device__ __forceinline__ void async_cp16(const bf16* g, bf16* l) {
    __builtin_amdgcn_global_load_lds(
        (const __attribute__((address_space(1))) void*)g,
        (__attribute__((address_space(3))) void*)l, 16, 0, 0);
}

// K/V^T tiled layout: per (bh, 64-key tile): [ch(0-7)][row(0-63)][8 elems].
#define TILE_OFF(bh, tile) (((size_t)(bh) * 32 + (tile)) * 4096)

// ---------------------------------------------------------------------------
__global__ __launch_bounds__(256) void mask_scan(const int* __restrict__ mask,
                                                 int* __restrict__ pos,
                                                 int* __restrict__ cnt)
{
    __shared__ int sums[256];
    const int tid = threadIdx.x;
    int v[8], s = 0;
    #pragma unroll
    for (int j = 0; j < 8; j++) { v[j] = mask[tid * 8 + j] ? 1 : 0; s += v[j]; }
    sums[tid] = s;
    __syncthreads();
    for (int off = 1; off < 256; off <<= 1) {
        int t = (tid >= off) ? sums[tid - off] : 0;
        __syncthreads();
        sums[tid] += t;
        __syncthreads();
    }
    int base = (tid > 0) ? sums[tid - 1] : 0;
    #pragma unroll
    for (int j = 0; j < 8; j++) { pos[tid * 8 + j] = base; base += v[j]; }
    if (tid == 255) cnt[0] = sums[255];
}

// ---------------------------------------------------------------------------
__global__ __launch_bounds__(256) void cvt6(
    const float* __restrict__ x0, const float* __restrict__ x1, const float* __restrict__ x2,
    const float* __restrict__ w0, const float* __restrict__ w1, const float* __restrict__ w2,
    bf16* __restrict__ o0, bf16* __restrict__ o1, bf16* __restrict__ o2,
    bf16* __restrict__ o3, bf16* __restrict__ o4, bf16* __restrict__ o5)
{
    const int z = blockIdx.y;
    if (z >= 3 && blockIdx.x >= 512) return;   // W tensors are 1/4 size
    const float* src = (z == 0) ? x0 : (z == 1) ? x1 : (z == 2) ? x2
                     : (z == 3) ? w0 : (z == 4) ? w1 : w2;
    bf16* dst = (z == 0) ? o0 : (z == 1) ? o1 : (z == 2) ? o2
              : (z == 3) ? o3 : (z == 4) ? o4 : o5;
    const size_t i = ((size_t)blockIdx.x * 256 + threadIdx.x) * 8;
    floatx4 a = *(const floatx4*)(src + i);
    floatx4 b = *(const floatx4*)(src + i + 4);
    bf16x8 v;
    #pragma unroll
    for (int j = 0; j < 4; j++) { v[j] = (bf16)a[j]; v[4 + j] = (bf16)b[j]; }
    *(bf16x8*)(dst + i) = v;
}

#define TM 128
#define TN 64
#define BK 32

// ---------------------------------------------------------------------------
__global__ __launch_bounds__(256, 4) void qkv_gemm_async(
    const bf16* __restrict__ xq, const bf16* __restrict__ xk, const bf16* __restrict__ xv,
    const bf16* __restrict__ wq, const bf16* __restrict__ wk, const bf16* __restrict__ wv,
    const float* __restrict__ bq, const float* __restrict__ bk, const float* __restrict__ bv,
    const int* __restrict__ mask, const int* __restrict__ pos,
    bf16* __restrict__ oq, bf16* __restrict__ ok, bf16* __restrict__ ov)
{
    __shared__ __align__(16) bf16 a_lds[TM * BK];   // 8 KB
    __shared__ __align__(16) bf16 b_lds[TN * BK];   // 4 KB

    const int fid = blockIdx.x;
    const int xcd = fid & 7;
    const int t   = fid >> 3;      // 0..191
    const int z   = t >> 6;        // 0..2
    const int u   = t & 63;
    const int m0  = ((u & 3) * 8 + xcd) * TM;
    const int n0  = (u >> 2) * TN;

    const bf16*  X  = (z == 0) ? xq : (z == 1) ? xk : xv;
    const bf16*  W  = (z == 0) ? wq : (z == 1) ? wk : wv;
    const float* Bi = (z == 0) ? bq : (z == 1) ? bk : bv;

    const int tid  = threadIdx.x;
    const int wid  = tid >> 6;
    const int lane = tid & 63;
    const int wm = wid >> 1, wn = wid & 1;    // 2x2 waves over (128, 64)
    const int lm = lane & 15, lq = lane >> 4;
    const int ksw = lq ^ ((lm >> 1) & 3);     // swizzled frag k-chunk

    floatx4 acc[4][2] = {};

    for (int kt = 0; kt < D_; kt += BK) {
        __syncthreads();
        #pragma unroll
        for (int tt = 0; tt < 2; tt++) {
            const int cb = (tt * 4 + wid) * 64;
            const int c  = cb + lane;
            const int row = c >> 2, kc = (c & 3) ^ ((c >> 3) & 3);
            async_cp16(X + (size_t)(m0 + row) * D_ + kt + kc * 8, a_lds + cb * 8);
        }
        {
            const int cb = wid * 64;
            const int c  = cb + lane;
            const int row = c >> 2, kc = (c & 3) ^ ((c >> 3) & 3);
            async_cp16(W + (size_t)(n0 + row) * D_ + kt + kc * 8, b_lds + cb * 8);
        }
        __syncthreads();   // drains vmcnt for global_load_lds

        bf16x8 af[4], bf[2];
        #pragma unroll
        for (int i = 0; i < 4; i++)
            af[i] = *(const bf16x8*)(a_lds + (wm * 64 + i * 16 + lm) * 32 + ksw * 8);
        #pragma unroll
        for (int j = 0; j < 2; j++)
            bf[j] = *(const bf16x8*)(b_lds + (wn * 32 + j * 16 + lm) * 32 + ksw * 8);
        #pragma unroll
        for (int i = 0; i < 4; i++)
            #pragma unroll
            for (int j = 0; j < 2; j++)
                acc[i][j] = __builtin_amdgcn_mfma_f32_16x16x32_bf16(
                    af[i], bf[j], acc[i][j], 0, 0, 0);
    }

    // C/D layout: col = lm (W side), row = lq*4 + r (X side)
    #pragma unroll
    for (int j = 0; j < 2; j++) {
        const int n = n0 + wn * 32 + j * 16 + lm;   // W row
        const float bias = Bi[n];
        const int h = n >> 6, hd = n & 63;
        #pragma unroll
        for (int i = 0; i < 4; i++) {
            const int mb = m0 + wm * 64 + i * 16 + lq * 4;
            #pragma unroll
            for (int r = 0; r < 4; r++) {
                const int m = mb + r;              // X row
                const int s = m >> 1, b = m & 1;
                const float v = acc[i][j][r] + bias;
                const int bh = b * H_ + h;
                if (z == 0) {
                    oq[((size_t)bh * S_ + s) * HD_ + hd] = (bf16)(v * QSCALE);
                } else if (mask[s]) {
                    const int cs = pos[s];
                    if (z == 1) {
                        ok[TILE_OFF(bh, cs >> 6) + (hd >> 3) * 512 +
                           (cs & 63) * 8 + (hd & 7)] = (bf16)v;
                    } else {
                        ov[TILE_OFF(bh, cs >> 6) + ((cs >> 3) & 7) * 512 +
                           hd * 8 + (cs & 7)] = (bf16)v;
                    }
                }
            }
        }
    }
}

// ---------------------------------------------------------------------------
__global__ __launch_bounds__(256, 4) void attn_kernel(
    const bf16* __restrict__ qw, const bf16* __restrict__ kw, const bf16* __restrict__ vtw,
    const int* __restrict__ cnt, float* __restrict__ out)
{
    __shared__ __align__(16) bf16 p_lds[4 * 16 * 72];   // wave-private P, 9 KB

    const int fid  = blockIdx.x;
    const int xcd  = fid & 7;
    const int t    = fid >> 3;
    const int bh   = (t & 3) * 8 + xcd;
    const int q0   = (t >> 2) * 64;

    const int tid  = threadIdx.x;
    const int wid  = tid >> 6;
    const int lane = tid & 63;
    const int lm = lane & 15, lq = lane >> 4;
    const int count = cnt[0];
    const int ntiles = (count + 63) >> 6;

    bf16x8 qf[2];
    {
        const bf16* qp = qw + ((size_t)bh * S_ + q0 + wid * 16 + lm) * HD_;
        qf[0] = *(const bf16x8*)(qp + lq * 8);
        qf[1] = *(const bf16x8*)(qp + 32 + lq * 8);
    }

    float lsum[4] = {0.f, 0.f, 0.f, 0.f};
    floatx4 oacc[4] = {};
    bf16* pw = p_lds + wid * 16 * 72;

    for (int tl = 0; tl < ntiles; tl++) {
        const size_t tbase = TILE_OFF(bh, tl);
        const size_t foff  = (size_t)lq * 512 + (size_t)lm * 8;

        // K frags (B-layout): K[key = n*16+lm][hd chunk = ks*4+lq]
        bf16x8 kf[2][4];
        #pragma unroll
        for (int ks = 0; ks < 2; ks++)
            #pragma unroll
            for (int n = 0; n < 4; n++)
                kf[ks][n] = *(const bf16x8*)(kw + tbase + ks * 2048 + foff + n * 128);

        // QK^T (C layout: row = q lq*4+r, col = key n*16+lm)
        floatx4 sacc[4] = {};
        #pragma unroll
        for (int ks = 0; ks < 2; ks++)
            #pragma unroll
            for (int n = 0; n < 4; n++)
                sacc[n] = __builtin_amdgcn_mfma_f32_16x16x32_bf16(
                    qf[ks], kf[ks][n], sacc[n], 0, 0, 0);

        // p = exp2(score); zero keys >= count (last tile only)
        const int jb = tl * 64;
        float valf[4];
        #pragma unroll
        for (int n = 0; n < 4; n++)
            valf[n] = (jb + n * 16 + lm < count) ? 1.0f : 0.0f;
        #pragma unroll
        for (int r = 0; r < 4; r++)
            #pragma unroll
            for (int n = 0; n < 4; n++) {
                const float p = exp2f(sacc[n][r]) * valf[n];
                lsum[r] += p;
                sacc[n][r] = p;
            }

        // V^T frags (B-layout): VT[d = n*16+lm][kj chunk = ks*4+lq]
        bf16x8 vf[2][4];
        #pragma unroll
        for (int ks = 0; ks < 2; ks++)
            #pragma unroll
            for (int n = 0; n < 4; n++)
                vf[ks][n] = *(const bf16x8*)(vtw + tbase + ks * 2048 + foff + n * 128);

        // P: C layout -> wave-private LDS -> A layout (no barrier needed)
        #pragma unroll
        for (int r = 0; r < 4; r++)
            #pragma unroll
            for (int n = 0; n < 4; n++)
                pw[(lq * 4 + r) * 72 + n * 16 + lm] = (bf16)sacc[n][r];

        #pragma unroll
        for (int ks = 0; ks < 2; ks++) {
            bf16x8 pf = *(const bf16x8*)(pw + lm * 72 + ks * 32 + lq * 8);
            #pragma unroll
            for (int n = 0; n < 4; n++)
                oacc[n] = __builtin_amdgcn_mfma_f32_16x16x32_bf16(
                    pf, vf[ks][n], oacc[n], 0, 0, 0);
        }
    }

    float invl[4];
    #pragma unroll
    for (int r = 0; r < 4; r++) {
        float lr = lsum[r];
        lr += __shfl_xor(lr, 1);
        lr += __shfl_xor(lr, 2);
        lr += __shfl_xor(lr, 4);
        lr += __shfl_xor(lr, 8);
        invl[r] = 1.0f / lr;
    }
    const int b = bh >> 4, h = bh & 15;
    #pragma unroll
    for (int n = 0; n < 4; n++)
        #pragma unroll
        for (int r = 0; r < 4; r++) {
            const int q = q0 + wid * 16 + lq * 4 + r;
            out[((size_t)q * B_ + b) * D_ + h * 64 + n * 16 + lm] = oacc[n][r] * invl[r];
        }
}

// ---------------------------------------------------------------------------
extern "C" void kernel_launch(void* const* d_in, const int* in_sizes, int n_in,
                              void* d_out, int out_size, void* d_ws, size_t ws_size,
                              hipStream_t stream) {
    const float* xq = (const float*)d_in[0];
    const float* xk = (const float*)d_in[1];
    const float* xv = (const float*)d_in[2];
    const int*  mask = (const int*)d_in[3];
    const float* wq = (const float*)d_in[4];
    const float* bq = (const float*)d_in[5];
    const float* wk = (const float*)d_in[6];
    const float* bk = (const float*)d_in[7];
    const float* wv = (const float*)d_in[8];
    const float* bv = (const float*)d_in[9];

    const size_t NX = (size_t)M_ * D_;      // 4194304
    const size_t NW = (size_t)D_ * D_;      // 1048576
    char* ws = (char*)d_ws;
    int* cnt = (int*)ws;
    int* pos = cnt + 16;
    char* base = ws + 16384;

    bf16* xqb = (bf16*)base;
    bf16* xkb = xqb + NX;
    bf16* xvb = xkb + NX;
    bf16* wqb = xvb + NX;
    bf16* wkb = wqb + NW;
    bf16* wvb = wkb + NW;
    bf16* q_ws  = wvb + NW;
    bf16* k_ws  = q_ws + NX;
    bf16* vt_ws = k_ws + NX;

    mask_scan<<<1, 256, 0, stream>>>(mask, pos, cnt);
    cvt6<<<dim3(2048, 6), 256, 0, stream>>>(xq, xk, xv, wq, wk, wv,
                                            xqb, xkb, xvb, wqb, wkb, wvb);
    qkv_gemm_async<<<1536, 256, 0, stream>>>(xqb, xkb, xvb, wqb, wkb, wvb,
                                             bq, bk, bv, mask, pos,
                                             q_ws, k_ws, vt_ws);
    attn_kernel<<<1024, 256, 0, stream>>>(q_ws, k_ws, vt_ws, cnt, (float*)d_out);
}